// Round 4
// baseline (65.570 us; speedup 1.0000x reference)
//
#include <hip/hip_runtime.h>
#include <cmath>

// Problem constants (fixed by setup_inputs)
#define BB 32
#define EE 256
#define NC 1024
#define NF 4096
#define TOKSTRIDE 5120   // Nc+Nf rows per batch
#define IMG 256

// ---------------- K1: coarse GEMM -> coarse image (pre-conv) ----------------
__global__ __launch_bounds__(256) void k_coarse(const float* __restrict__ tokens,
                                                const float* __restrict__ Wc,
                                                const float* __restrict__ bc,
                                                float* __restrict__ coarse_img) {
    __shared__ float tok[32][260];
    const int tid = threadIdx.x;
    const int tokbase = blockIdx.x * 32;
    const int b  = tokbase >> 10;
    const int t0 = tokbase & 1023;
    const float* src = tokens + ((size_t)b * TOKSTRIDE + t0) * EE;

    #pragma unroll
    for (int i = 0; i < 8; ++i) {
        int f = i * 1024 + tid * 4;
        int r = f >> 8, c = f & 255;
        float4 v = *reinterpret_cast<const float4*>(src + f);
        *reinterpret_cast<float4*>(&tok[r][c]) = v;
    }
    __syncthreads();

    const int wave = tid >> 6;
    const int lane = tid & 63;
    float acc[8] = {0.f,0.f,0.f,0.f,0.f,0.f,0.f,0.f};

    for (int k = 0; k < 256; k += 4) {
        float w0 = Wc[(k+0)*64 + lane];
        float w1 = Wc[(k+1)*64 + lane];
        float w2 = Wc[(k+2)*64 + lane];
        float w3 = Wc[(k+3)*64 + lane];
        #pragma unroll
        for (int t = 0; t < 8; ++t) {
            const float* tp = &tok[wave*8 + t][k];
            float4 t4 = *reinterpret_cast<const float4*>(tp);
            acc[t] = fmaf(t4.x, w0, acc[t]);
            acc[t] = fmaf(t4.y, w1, acc[t]);
            acc[t] = fmaf(t4.z, w2, acc[t]);
            acc[t] = fmaf(t4.w, w3, acc[t]);
        }
    }

    const float bias = bc[lane];
    const int ph = lane >> 3, pw = lane & 7;
    #pragma unroll
    for (int t = 0; t < 8; ++t) {
        int tg = t0 + wave*8 + t;
        int hc = tg >> 5, wc = tg & 31;
        int h = hc*8 + ph, w = wc*8 + pw;
        coarse_img[(size_t)b*65536 + h*256 + w] = acc[t] + bias;
    }
}

// ---------------- K2: per-batch inclusive cumsum of mask ----------------
__global__ __launch_bounds__(256) void k_scan(const int* __restrict__ mask,
                                              int* __restrict__ cum) {
    __shared__ int sums[256];
    const int b = blockIdx.x;
    const int tid = threadIdx.x;
    const int* m = mask + b * NF;

    int loc[16];
    int s = 0;
    #pragma unroll
    for (int i = 0; i < 16; ++i) { int v = (m[tid*16 + i] != 0) ? 1 : 0; s += v; loc[i] = s; }
    sums[tid] = s;
    __syncthreads();

    for (int off = 1; off < 256; off <<= 1) {
        int v = sums[tid];
        int add = (tid >= off) ? sums[tid - off] : 0;
        __syncthreads();
        sums[tid] = v + add;
        __syncthreads();
    }
    int excl = sums[tid] - s;
    #pragma unroll
    for (int i = 0; i < 16; ++i) cum[b*NF + tid*16 + i] = excl + loc[i];
}

// ---------------- K3: dense fine GEMM, thread-per-(row, K-half) ----------------
// patch[b][row][16] = fine_tokens[b][row] @ Wf + bf for row < cnt[b].
// X streamed global->registers (no staging barrier); Wf LDS-broadcast;
// K split across half-waves, combined with __shfl_xor(.,32).
__global__ __launch_bounds__(256) void k_gemm(const float* __restrict__ tokens,
                                              const int* __restrict__ cum,
                                              const float* __restrict__ Wf,
                                              const float* __restrict__ bf,
                                              float* __restrict__ patch) {
    const int b   = blockIdx.x >> 5;           // 32 tiles/batch, 128 rows each
    const int r0  = (blockIdx.x & 31) * 128;
    const int cnt = cum[b*NF + NF - 1];
    if (r0 >= cnt) return;

    __shared__ float Wl[256*16];               // 16 KB
    const int tid = threadIdx.x;
    #pragma unroll
    for (int i = 0; i < 4; ++i) {
        int f = i*1024 + tid*4;
        *reinterpret_cast<float4*>(&Wl[f]) = *reinterpret_cast<const float4*>(Wf + f);
    }
    __syncthreads();

    const int wave = tid >> 6;
    const int lane = tid & 63;
    const int rloc = wave*32 + (lane & 31);
    const int kh   = lane >> 5;                // K half
    const int row  = r0 + rloc;

    const float* xp = tokens + ((size_t)b*TOKSTRIDE + NC + row)*EE + kh*128;

    float acc[16];
    #pragma unroll
    for (int c = 0; c < 16; ++c) acc[c] = 0.f;

    #pragma unroll 2
    for (int k = 0; k < 128; k += 4) {
        float4 x = *reinterpret_cast<const float4*>(xp + k);
        const float* wrow = &Wl[(kh*128 + k)*16];
        #pragma unroll
        for (int kk = 0; kk < 4; ++kk) {
            const float xv = (&x.x)[kk];
            float4 w0 = *reinterpret_cast<const float4*>(wrow + kk*16 + 0);
            float4 w1 = *reinterpret_cast<const float4*>(wrow + kk*16 + 4);
            float4 w2 = *reinterpret_cast<const float4*>(wrow + kk*16 + 8);
            float4 w3 = *reinterpret_cast<const float4*>(wrow + kk*16 + 12);
            acc[0]  = fmaf(xv, w0.x, acc[0]);
            acc[1]  = fmaf(xv, w0.y, acc[1]);
            acc[2]  = fmaf(xv, w0.z, acc[2]);
            acc[3]  = fmaf(xv, w0.w, acc[3]);
            acc[4]  = fmaf(xv, w1.x, acc[4]);
            acc[5]  = fmaf(xv, w1.y, acc[5]);
            acc[6]  = fmaf(xv, w1.z, acc[6]);
            acc[7]  = fmaf(xv, w1.w, acc[7]);
            acc[8]  = fmaf(xv, w2.x, acc[8]);
            acc[9]  = fmaf(xv, w2.y, acc[9]);
            acc[10] = fmaf(xv, w2.z, acc[10]);
            acc[11] = fmaf(xv, w2.w, acc[11]);
            acc[12] = fmaf(xv, w3.x, acc[12]);
            acc[13] = fmaf(xv, w3.y, acc[13]);
            acc[14] = fmaf(xv, w3.z, acc[14]);
            acc[15] = fmaf(xv, w3.w, acc[15]);
        }
    }

    #pragma unroll
    for (int c = 0; c < 16; ++c) acc[c] += __shfl_xor(acc[c], 32, 64);

    if (kh == 0) {
        float* dst = &patch[((size_t)b*NF + row)*16];
        float4 o0 = make_float4(acc[0] +bf[0],  acc[1] +bf[1],  acc[2] +bf[2],  acc[3] +bf[3]);
        float4 o1 = make_float4(acc[4] +bf[4],  acc[5] +bf[5],  acc[6] +bf[6],  acc[7] +bf[7]);
        float4 o2 = make_float4(acc[8] +bf[8],  acc[9] +bf[9],  acc[10]+bf[10], acc[11]+bf[11]);
        float4 o3 = make_float4(acc[12]+bf[12], acc[13]+bf[13], acc[14]+bf[14], acc[15]+bf[15]);
        *reinterpret_cast<float4*>(dst + 0)  = o0;
        *reinterpret_cast<float4*>(dst + 4)  = o1;
        *reinterpret_cast<float4*>(dst + 8)  = o2;
        *reinterpret_cast<float4*>(dst + 12) = o3;
    }
}

// ---------------- K4: fused scatter + conv + blend + downsample ----------------
struct InterpArgs { int i0[32]; int i1[32]; float fr[32]; };

__global__ __launch_bounds__(128) void k_out(const float* __restrict__ coarse_img,
                                             const float* __restrict__ patch,
                                             const int* __restrict__ mask,
                                             const int* __restrict__ cum,
                                             const float* __restrict__ noise,
                                             const float* __restrict__ convw,
                                             float* __restrict__ out,
                                             InterpArgs ia) {
    const int tid = blockIdx.x * 128 + threadIdx.x;   // 32768
    const int b = tid >> 10;
    const int p = (tid >> 5) & 31;
    const int q = tid & 31;

    float kk[9];
    #pragma unroll
    for (int i = 0; i < 9; ++i) kk[i] = convw[i];

    const int   hs[2]  = { ia.i0[p], ia.i1[p] };
    const float fh     = ia.fr[p];
    const float wh[2]  = { 1.f - fh, fh };
    const int   wsx[2] = { ia.i0[q], ia.i1[q] };
    const float fw     = ia.fr[q];
    const float ww[2]  = { 1.f - fw, fw };

    const float* cimg = coarse_img + (size_t)b*65536;
    const float* nimg = noise      + (size_t)b*65536;

    float acc = 0.f;
    #pragma unroll
    for (int a = 0; a < 2; ++a) {
        #pragma unroll
        for (int c = 0; c < 2; ++c) {
            const int h = hs[a], w = wsx[c];
            float conv = 0.f;
            #pragma unroll
            for (int dh = -1; dh <= 1; ++dh) {
                #pragma unroll
                for (int dw = -1; dw <= 1; ++dw) {
                    int hh = h + dh, wp = w + dw;
                    float v = (hh >= 0 && hh < IMG && wp >= 0 && wp < IMG)
                              ? cimg[hh*IMG + wp] : 0.f;
                    conv = fmaf(v, kk[(dh+1)*3 + (dw+1)], conv);
                }
            }
            const int j = (h >> 2) * 64 + (w >> 2);
            float fv = 0.f;
            if (mask[b*NF + j] != 0) {
                int rk  = cum[b*NF + j] - 1;
                int col = (h & 3) * 4 + (w & 3);
                fv = patch[((size_t)b*NF + rk)*16 + col];
            }
            float s = 1.f / (1.f + expf(-0.1f * nimg[h*IMG + w]));
            acc += wh[a] * ww[c] * (conv * (1.f - s) + fv * s);
        }
    }
    out[tid] = acc;
}

extern "C" void kernel_launch(void* const* d_in, const int* in_sizes, int n_in,
                              void* d_out, int out_size, void* d_ws, size_t ws_size,
                              hipStream_t stream) {
    const float* tokens = (const float*)d_in[0];
    const int*   mask   = (const int*)  d_in[1];
    const float* Wc     = (const float*)d_in[2];
    const float* bc     = (const float*)d_in[3];
    const float* Wf     = (const float*)d_in[4];
    const float* bf     = (const float*)d_in[5];
    const float* convw  = (const float*)d_in[6];
    const float* noise  = (const float*)d_in[7];

    float* ws = (float*)d_ws;
    float* coarse_img = ws;                               // 32*65536 floats
    float* patch      = ws + (size_t)BB*65536;            // 32*4096*16 floats
    int*   cum        = (int*)(ws + (size_t)2*BB*65536);  // 32*4096 ints

    k_coarse<<<1024, 256, 0, stream>>>(tokens, Wc, bc, coarse_img);
    k_scan  <<<32,   256, 0, stream>>>(mask, cum);
    k_gemm  <<<1024, 256, 0, stream>>>(tokens, cum, Wf, bf, patch);

    InterpArgs ia;
    for (int p = 0; p < 32; ++p) {
        double pos = (double)p * 255.0 / 31.0;
        int i0 = (int)floor(pos);
        int i1 = (i0 + 1 < 256) ? i0 + 1 : 255;
        ia.i0[p] = i0; ia.i1[p] = i1; ia.fr[p] = (float)(pos - (double)i0);
    }
    k_out<<<256, 128, 0, stream>>>(coarse_img, patch, mask, cum, noise, convw,
                                   (float*)d_out, ia);
}